// Round 5
// baseline (181.535 us; speedup 1.0000x reference)
//
#include <hip/hip_runtime.h>

#define B_DIM 1024
#define C_DIM 256
#define ELL   9
#define E_DIM 10
#define K1    1
#define K2    4
#define K3    20

#define N_CUBIC 165                 // monomials a<=b<=c
#define N_QUAD  45                  // pairs a<=b
// q-sliced table layout: per q: [165*20 cubic][45*4 quad][9 lin][3 pad]
#define Q_CUBIC 0
#define Q_QUAD  (N_CUBIC * K3)              // 3300
#define Q_LIN   (Q_QUAD + N_QUAD * K2)      // 3480
#define Q_SIZE  3492                        // padded to 16B multiple
#define TBL_FLOATS (4 * Q_SIZE)             // 13968
#define MONO3_OFF  TBL_FLOATS               // int region after floats
#define MONO2_OFF  (MONO3_OFF + N_CUBIC)
#define WS_TOTAL   (MONO2_OFF + N_QUAD)     // 14178 words

// ---------------------------------------------------------------------------
// Kernel A: build q-sliced symmetrized tables + packed monomial decode words.
// ---------------------------------------------------------------------------
__global__ void build_tables(const float* __restrict__ U1_l0,
                             const float* __restrict__ U2_l0,
                             const float* __restrict__ U3_l0,
                             const float* __restrict__ U1_l1,
                             const float* __restrict__ U2_l1,
                             const float* __restrict__ U3_l1,
                             float* __restrict__ tbl)
{
    int idx = blockIdx.x * blockDim.x + threadIdx.x;
    if (idx >= WS_TOTAL) return;

    if (idx < TBL_FLOATS) {
        int q = idx / Q_SIZE;       // 0 = l0; 1..3 = l1 v=q-1
        int r = idx % Q_SIZE;
        int v = q - 1;
        float s = 0.f;
        if (r < Q_QUAD) {
            int m = r / K3, k = r % K3;
            int a = 0, b = 0, c = 0, cnt = 0;
            for (int ai = 0; ai < ELL; ++ai)
                for (int bi = ai; bi < ELL; ++bi)
                    for (int ci = bi; ci < ELL; ++ci) {
                        if (cnt == m) { a = ai; b = bi; c = ci; }
                        ++cnt;
                    }
            int P[6][3] = {{a,b,c},{a,c,b},{b,a,c},{b,c,a},{c,a,b},{c,b,a}};
            for (int t = 0; t < 6; ++t) {
                bool dup = false;
                for (int u = 0; u < t; ++u)
                    if (P[u][0]==P[t][0] && P[u][1]==P[t][1] && P[u][2]==P[t][2]) { dup = true; break; }
                if (dup) continue;
                int p0 = P[t][0], p1 = P[t][1], p2 = P[t][2];
                if (q == 0) s += U3_l0[((p0*ELL + p1)*ELL + p2)*K3 + k];
                else        s += U3_l1[(((v*ELL + p0)*ELL + p1)*ELL + p2)*K3 + k];
            }
        } else if (r < Q_LIN) {
            int rr = r - Q_QUAD;
            int p = rr / K2, k = rr % K2;
            int a = 0, b = 0, cnt = 0;
            for (int ai = 0; ai < ELL; ++ai)
                for (int bi = ai; bi < ELL; ++bi) {
                    if (cnt == p) { a = ai; b = bi; }
                    ++cnt;
                }
            for (int t = 0; t < 2; ++t) {
                if (t == 1 && a == b) break;
                int p0 = (t == 0) ? a : b;
                int p1 = (t == 0) ? b : a;
                if (q == 0) s += U2_l0[(p0*ELL + p1)*K2 + k];
                else        s += U2_l1[((v*ELL + p0)*ELL + p1)*K2 + k];
            }
        } else if (r < Q_LIN + ELL) {
            int i = r - Q_LIN;
            s = (q == 0) ? U1_l0[i] : U1_l1[v*ELL + i];
        } else {
            s = 0.f;   // pad
        }
        tbl[idx] = s;
    } else if (idx < MONO2_OFF) {
        int m = idx - MONO3_OFF;
        int a = 0, b = 0, c = 0, cnt = 0;
        for (int ai = 0; ai < ELL; ++ai)
            for (int bi = ai; bi < ELL; ++bi)
                for (int ci = bi; ci < ELL; ++ci) {
                    if (cnt == m) { a = ai; b = bi; c = ci; }
                    ++cnt;
                }
        ((int*)tbl)[idx] = a | (b << 4) | (c << 8);
    } else {
        int p = idx - MONO2_OFF;
        int a = 0, b = 0, cnt = 0;
        for (int ai = 0; ai < ELL; ++ai)
            for (int bi = ai; bi < ELL; ++bi) {
                if (cnt == p) { a = ai; b = bi; }
                ++cnt;
            }
        ((int*)tbl)[idx] = a | (b << 4);
    }
}

// ---------------------------------------------------------------------------
// Kernel B v5: 512-thread block = (b, c-half). q = readfirstlane(tid>>7).
// Table lives in LDS; rows read with UNIFORM-address ds_read (broadcast,
// conflict-free, lands in VGPRs -> v_fmac). Scalar pipe only carries the
// 1 s_load/iter of the packed monomial word. x staged in LDS (runtime index,
// rule #20). Combine computes w~ per-thread from L2-hot weight arrays.
// ---------------------------------------------------------------------------
__global__ __launch_bounds__(512, 4) void symcon_main(
    const float* __restrict__ x,  const float* __restrict__ y,
    const float* __restrict__ w1_l0, const float* __restrict__ w2_l0, const float* __restrict__ w3_l0,
    const float* __restrict__ w1_l1, const float* __restrict__ w2_l1, const float* __restrict__ w3_l1,
    const float* __restrict__ tbl, const int* __restrict__ mono3,
    const int* __restrict__ mono2, float* __restrict__ out)
{
    const int bid = blockIdx.x;
    const int b   = bid >> 1;
    const int ch  = bid & 1;                 // which half of C
    const int tid = threadIdx.x;
    const int q   = __builtin_amdgcn_readfirstlane(tid >> 7);  // 0..3, SGPR
    const int ci  = tid & 127;
    const int c   = (ch << 7) + ci;

    __shared__ float lt[TBL_FLOATS];         // 55.9 KB
    __shared__ float xs[ELL][128];           //  4.6 KB

    for (int t = tid; t < TBL_FLOATS; t += 512) lt[t] = tbl[t];
    for (int t = tid; t < ELL * 128; t += 512) {
        int i  = t >> 7;
        int cc = t & 127;
        xs[i][cc] = x[(size_t)(b*C_DIM + (ch << 7) + cc)*ELL + i];
    }
    __syncthreads();

    float acc3[K3];
    #pragma unroll
    for (int j = 0; j < K3; ++j) acc3[j] = 0.f;
    float acc2[K2];
    #pragma unroll
    for (int j = 0; j < K2; ++j) acc2[j] = 0.f;
    float acc1 = 0.f;

    const float* tq = &lt[q * Q_SIZE];       // wave-uniform LDS base

    // ---- cubic: 165 monomials ----
    #pragma unroll 2
    for (int m = 0; m < N_CUBIC; ++m) {
        int e3 = mono3[m];                   // uniform -> s_load
        float xa = xs[e3 & 15][ci];
        float xb = xs[(e3 >> 4) & 15][ci];
        float xc = xs[(e3 >> 8) & 15][ci];
        float x3 = xa * xb * xc;
        const float* r = &tq[Q_CUBIC + m*K3];
        #pragma unroll
        for (int j = 0; j < K3; ++j)
            acc3[j] = fmaf(r[j], x3, acc3[j]);
    }
    // ---- quadratic: 45 monomials ----
    #pragma unroll 2
    for (int p = 0; p < N_QUAD; ++p) {
        int e2 = mono2[p];
        float x2 = xs[e2 & 15][ci] * xs[(e2 >> 4) & 15][ci];
        const float* r = &tq[Q_QUAD + p*K2];
        #pragma unroll
        for (int j = 0; j < K2; ++j)
            acc2[j] = fmaf(r[j], x2, acc2[j]);
    }
    // ---- linear ----
    #pragma unroll
    for (int i = 0; i < ELL; ++i)
        acc1 = fmaf(tq[Q_LIN + i], xs[i][ci], acc1);

    // ---- combine: w~[k,c] on the fly ----
    const float* w3 = (q == 0) ? w3_l0 : w3_l1;
    const float* w2 = (q == 0) ? w2_l0 : w2_l1;
    const float* w1 = (q == 0) ? w1_l0 : w1_l1;

    float yb[E_DIM];
    #pragma unroll
    for (int e = 0; e < E_DIM; ++e) yb[e] = y[b*E_DIM + e];

    float o = 0.f;
    #pragma unroll
    for (int k = 0; k < K3; ++k) {
        float wt = 0.f;
        #pragma unroll
        for (int e = 0; e < E_DIM; ++e)
            wt = fmaf(yb[e], w3[(e*K3 + k)*C_DIM + c], wt);
        o = fmaf(wt, acc3[k], o);
    }
    #pragma unroll
    for (int k = 0; k < K2; ++k) {
        float wt = 0.f;
        #pragma unroll
        for (int e = 0; e < E_DIM; ++e)
            wt = fmaf(yb[e], w2[(e*K2 + k)*C_DIM + c], wt);
        o = fmaf(wt, acc2[k], o);
    }
    {
        float wt = 0.f;
        #pragma unroll
        for (int e = 0; e < E_DIM; ++e)
            wt = fmaf(yb[e], w1[e*C_DIM + c], wt);
        o = fmaf(wt, acc1, o);
    }

    if (q == 0) {
        out[b*C_DIM + c] = o;
    } else {
        out[B_DIM*C_DIM + (size_t)(b*C_DIM + c)*3 + (q - 1)] = o;
    }
}

// ---------------------------------------------------------------------------
extern "C" void kernel_launch(void* const* d_in, const int* in_sizes, int n_in,
                              void* d_out, int out_size, void* d_ws, size_t ws_size,
                              hipStream_t stream)
{
    const float* x     = (const float*)d_in[0];
    const float* y     = (const float*)d_in[1];
    const float* U1_l0 = (const float*)d_in[2];
    const float* U2_l0 = (const float*)d_in[3];
    const float* U3_l0 = (const float*)d_in[4];
    const float* U1_l1 = (const float*)d_in[5];
    const float* U2_l1 = (const float*)d_in[6];
    const float* U3_l1 = (const float*)d_in[7];
    const float* w1_l0 = (const float*)d_in[8];
    const float* w2_l0 = (const float*)d_in[9];
    const float* w3_l0 = (const float*)d_in[10];
    const float* w1_l1 = (const float*)d_in[11];
    const float* w2_l1 = (const float*)d_in[12];
    const float* w3_l1 = (const float*)d_in[13];

    float* tbl = (float*)d_ws;               // 56.7 KB used
    const int* mono3 = (const int*)((float*)d_ws + MONO3_OFF);
    const int* mono2 = (const int*)((float*)d_ws + MONO2_OFF);
    float* outp = (float*)d_out;

    build_tables<<<(WS_TOTAL + 255)/256, 256, 0, stream>>>(
        U1_l0, U2_l0, U3_l0, U1_l1, U2_l1, U3_l1, tbl);

    symcon_main<<<2*B_DIM, 512, 0, stream>>>(
        x, y, w1_l0, w2_l0, w3_l0, w1_l1, w2_l1, w3_l1, tbl, mono3, mono2, outp);
}